// Round 2
// baseline (229.101 us; speedup 1.0000x reference)
//
#include <hip/hip_runtime.h>
#include <stdint.h>
#include <math.h>

// HashingDiscretizer — R7: R6 phase-separated structure + correct VGPR budget.
//
// R6 post-mortem: VGPR_Count=64 + FETCH/WRITE inflated by ~250MB = the
// compiler capped registers at its default 8-waves/EU occupancy target and
// spilled the phase-separated live set (hdr[8], gA/gB[8]) to scratch every
// chunk. But LDS (139KB -> 1 block/CU -> 16 waves -> 4 waves/SIMD) already
// caps occupancy at 4 waves/EU, so the 64-VGPR cap bought nothing.
// Fix: __launch_bounds__(1024, 4) -> 128-VGPR budget, no spills.
//
// Structure (unchanged from R6):
//   P1: 8x ds_read_b128 spiv headers (all issued back-to-back)
//   P2: classify + quadrant + gather byte-offset (dummy offset 0 for
//       uncalibrated lanes -> wave-uniform line, coalesces in TA)
//   P3: 16x global_load_dwordx4 (stage 1: first 32B of quadrant line)
//   P4: partial strict-less counts (8 of 16 bins)
//   P5: 16x global_load_dwordx4 (stage 2: last 32B, reusing registers)
//   P6: finish counts + hash + branchless select
//   cold: rare mask (key>=16384 or calibrated high key; absent in bench
//         data) -> generic fallback loop.
//
// ws layout:
//   qtab  [8192][64] f32 (2 MB): row k = 63 boundaries + inf pad; the
//          quadrant q (16 floats at +16q) is ONE 64B line.
//   spiv  [8192] uint4 (128 KB): {f32 b15, f32 b31, f32 b47, u32 k^MAGIC}
//   scal  [8192] bytes  (8 KB): for keys 8192..16383: 0x40|(k&63)
// Poison 0xAA can match neither sentinel, so unwritten rows read as
// uncalibrated — no clear pass needed.

#define GOLDEN   0x9E3779B9u
#define OUT_MASK ((1u << 22) - 1u)
#define NBIN  63
#define NPIV  8192
#define NKEY  16384
#define MAGIC 0xC0FFEE42u

typedef float fx4 __attribute__((ext_vector_type(4)));
typedef int   ix4 __attribute__((ext_vector_type(4)));
typedef unsigned ux4 __attribute__((ext_vector_type(4)));

// ---------------- build (no atomics, no clear) ----------------
__global__ __launch_bounds__(256) void build_tables_kernel(
    const int* __restrict__ fids, const float* __restrict__ bins,
    float* __restrict__ qtab, ux4* __restrict__ spiv_g,
    unsigned char* __restrict__ scal_g, int F)
{
    const int t = blockIdx.x * blockDim.x + threadIdx.x;
    if (t >= F * 64) return;
    const int r = t >> 6;
    const int j = t & 63;
    const int k = fids[r];
    const unsigned uk = (unsigned)k;
    const float* src = bins + (size_t)r * NBIN;

    if (uk < (unsigned)NPIV) {
        qtab[((size_t)uk << 6) + j] = (j < NBIN) ? src[j] : INFINITY;
        if (j == 0) {
            ux4 p;
            p.x = __float_as_uint(src[15]);
            p.y = __float_as_uint(src[31]);
            p.z = __float_as_uint(src[47]);
            p.w = uk ^ MAGIC;
            spiv_g[uk] = p;
        }
    } else if (uk < (unsigned)NKEY && j == 0) {
        scal_g[uk - NPIV] = (unsigned char)(0x40u | (uk & 63u));
    }
}

// ---------------- generic fallback ----------------
__device__ __forceinline__ void hd_fallback(
    int k, float v, const int* __restrict__ fids, const float* __restrict__ bins,
    int F, int fsteps, float& okey, float& oval)
{
    int lo = 0, hi = F;
    for (int s = 0; s < fsteps; ++s) {
        int  mid  = (lo + hi) >> 1;
        int  mids = min(mid, F - 1);
        int  fv   = fids[mids];
        bool valid = lo < hi;
        bool right = valid && (fv < k);
        lo = right ? mid + 1 : lo;
        hi = (valid && !right) ? mid : hi;
    }
    const int  idx_safe   = min(lo, F - 1);
    const bool calibrated = (fids[idx_safe] == k);
    const float* brow = bins + (size_t)idx_safe * NBIN;
    int blo = 0, bhi = NBIN;
    #pragma unroll
    for (int s = 0; s < 6; ++s) {
        int   mid  = (blo + bhi) >> 1;
        int   mids = min(mid, NBIN - 1);
        float bv   = brow[mids];
        bool  valid = blo < bhi;
        bool  right = valid && (bv < v);
        blo = right ? mid + 1 : blo;
        bhi = (valid && !right) ? mid : bhi;
    }
    const uint32_t h = ((uint32_t)k * GOLDEN + (uint32_t)blo) * GOLDEN;
    okey = calibrated ? (float)(h & OUT_MASK) : (float)((uint32_t)k & OUT_MASK);
    oval = calibrated ? 1.0f : v;
}

// ---------------- main ----------------
// LDS (139KB) forces 1 block/CU = 4 waves/SIMD; declare it so the register
// allocator uses the full 512/4 = 128 VGPR budget instead of spilling.
__global__ __launch_bounds__(1024, 4) void hd_main_kernel(
    const int* __restrict__ keys, const float* __restrict__ vals,
    const int* __restrict__ fids, const float* __restrict__ bins,
    const float* __restrict__ qtab, const ux4* __restrict__ spiv_g,
    const unsigned char* __restrict__ scal_g,
    float* __restrict__ out_keys, float* __restrict__ out_vals,
    int n, int F, int fsteps, int nchunks)
{
    extern __shared__ char smem[];
    ux4*      spiv = reinterpret_cast<ux4*>(smem);               // NPIV x 16B
    unsigned* scal = reinterpret_cast<unsigned*>(smem + (size_t)NPIV * 16);

    const int tid = threadIdx.x;
    for (int i = tid; i < NPIV; i += (int)blockDim.x) spiv[i] = spiv_g[i];
    const unsigned* scal_g32 = reinterpret_cast<const unsigned*>(scal_g);
    for (int i = tid; i < NPIV / 4; i += (int)blockDim.x) scal[i] = scal_g32[i];
    __syncthreads();

    const unsigned char* scal_b = reinterpret_cast<const unsigned char*>(scal);
    const char* qb = reinterpret_cast<const char*>(qtab);
    const int nthreads = (int)(gridDim.x * blockDim.x);

    for (int c = blockIdx.x * blockDim.x + tid; c < nchunks; c += nthreads) {
        const int i0 = c * 8;
        int   ks[8];
        float vs[8];
        const bool full = (i0 + 7 < n);
        if (full) {
            const ix4 ka = __builtin_nontemporal_load(reinterpret_cast<const ix4*>(keys + i0));
            const ix4 kb = __builtin_nontemporal_load(reinterpret_cast<const ix4*>(keys + i0 + 4));
            const fx4 va = __builtin_nontemporal_load(reinterpret_cast<const fx4*>(vals + i0));
            const fx4 vb = __builtin_nontemporal_load(reinterpret_cast<const fx4*>(vals + i0 + 4));
            ks[0]=ka.x; ks[1]=ka.y; ks[2]=ka.z; ks[3]=ka.w;
            ks[4]=kb.x; ks[5]=kb.y; ks[6]=kb.z; ks[7]=kb.w;
            vs[0]=va.x; vs[1]=va.y; vs[2]=va.z; vs[3]=va.w;
            vs[4]=vb.x; vs[5]=vb.y; vs[6]=vb.z; vs[7]=vb.w;
        } else {
            #pragma unroll
            for (int j = 0; j < 8; ++j) {
                int idx = min(i0 + j, n - 1);
                ks[j] = keys[idx];
                vs[j] = vals[idx];
            }
        }

        // ---- P1: all 8 spiv headers (independent ds_read_b128) ----
        ux4 hdr[8];
        #pragma unroll
        for (int j = 0; j < 8; ++j) {
            const unsigned uk = (unsigned)ks[j];
            hdr[j] = spiv[uk < (unsigned)NPIV ? uk : 0u];
        }

        // ---- P2: classify, quadrant, byte offsets, rare mask ----
        unsigned off[8];
        int      qcnt[8];
        unsigned calm = 0u, rare = 0u;
        #pragma unroll
        for (int j = 0; j < 8; ++j) {
            const unsigned uk = (unsigned)ks[j];
            const float v = vs[j];
            const bool low = uk < (unsigned)NPIV;
            const bool cal = low && (hdr[j].w == (uk ^ MAGIC));
            const int q = (__uint_as_float(hdr[j].x) < v)
                        + (__uint_as_float(hdr[j].y) < v)
                        + (__uint_as_float(hdr[j].z) < v);
            off[j]  = cal ? ((uk << 8) + (unsigned)(q << 6)) : 0u;
            qcnt[j] = q << 4;
            calm   |= cal ? (1u << j) : 0u;
            // high-key calibrated check (LDS byte, branchless)
            const unsigned hs = uk - (unsigned)NPIV;
            const bool hi = hs < (unsigned)NPIV;            // NPIV<=uk<NKEY
            const bool calhi = hi && (scal_b[hi ? hs : 0u]
                              == (unsigned char)(0x40u | (uk & 63u)));
            rare |= (calhi || (uk >= (unsigned)NKEY)) ? (1u << j) : 0u;
        }

        // ---- P3: stage-1 gathers (first 32B of quadrant line) ----
        fx4 gA[8], gB[8];
        #pragma unroll
        for (int j = 0; j < 8; ++j) {
            const char* p = qb + off[j];
            gA[j] = *reinterpret_cast<const fx4*>(p);
            gB[j] = *reinterpret_cast<const fx4*>(p + 16);
        }
        // ---- P4: partial counts ----
        #pragma unroll
        for (int j = 0; j < 8; ++j) {
            const float v = vs[j];
            qcnt[j] += (gA[j].x<v)+(gA[j].y<v)+(gA[j].z<v)+(gA[j].w<v)
                     + (gB[j].x<v)+(gB[j].y<v)+(gB[j].z<v)+(gB[j].w<v);
        }
        // ---- P5: stage-2 gathers (last 32B, registers reused) ----
        #pragma unroll
        for (int j = 0; j < 8; ++j) {
            const char* p = qb + off[j];
            gA[j] = *reinterpret_cast<const fx4*>(p + 32);
            gB[j] = *reinterpret_cast<const fx4*>(p + 48);
        }
        // ---- P6: finish counts + hash + branchless select ----
        float ok[8], ov[8];
        #pragma unroll
        for (int j = 0; j < 8; ++j) {
            const unsigned uk = (unsigned)ks[j];
            const float v = vs[j];
            const int cnt = qcnt[j]
                + (gA[j].x<v)+(gA[j].y<v)+(gA[j].z<v)+(gA[j].w<v)
                + (gB[j].x<v)+(gB[j].y<v)+(gB[j].z<v)+(gB[j].w<v);
            const uint32_t h = (uk * GOLDEN + (uint32_t)cnt) * GOLDEN;
            const bool cal = (calm >> j) & 1u;
            ok[j] = cal ? (float)(h & OUT_MASK) : (float)(uk & OUT_MASK);
            ov[j] = cal ? 1.0f : v;
        }

        // ---- cold path: key>=NKEY or calibrated high key (never in bench)
        if (__builtin_expect(rare != 0u, 0)) {
            #pragma unroll 1
            for (int j = 0; j < 8; ++j)
                if ((rare >> j) & 1u)
                    hd_fallback(ks[j], vs[j], fids, bins, F, fsteps, ok[j], ov[j]);
        }

        if (full) {
            fx4 a, b;
            a.x=ok[0]; a.y=ok[1]; a.z=ok[2]; a.w=ok[3];
            b.x=ok[4]; b.y=ok[5]; b.z=ok[6]; b.w=ok[7];
            __builtin_nontemporal_store(a, reinterpret_cast<fx4*>(out_keys + i0));
            __builtin_nontemporal_store(b, reinterpret_cast<fx4*>(out_keys + i0 + 4));
            a.x=ov[0]; a.y=ov[1]; a.z=ov[2]; a.w=ov[3];
            b.x=ov[4]; b.y=ov[5]; b.z=ov[6]; b.w=ov[7];
            __builtin_nontemporal_store(a, reinterpret_cast<fx4*>(out_vals + i0));
            __builtin_nontemporal_store(b, reinterpret_cast<fx4*>(out_vals + i0 + 4));
        } else {
            for (int j = 0; j < 8 && i0 + j < n; ++j) {
                out_keys[i0 + j] = ok[j];
                out_vals[i0 + j] = ov[j];
            }
        }
    }
}

// Pure binary-search kernel: used only if LDS or workspace is insufficient.
__global__ __launch_bounds__(256) void hd_simple_kernel(
    const int* __restrict__ keys, const float* __restrict__ vals,
    const int* __restrict__ fids, const float* __restrict__ bins,
    float* __restrict__ out_keys, float* __restrict__ out_vals,
    int n, int F, int fsteps)
{
    const int gid = blockIdx.x * blockDim.x + threadIdx.x;
    const int i0 = gid * 4;
    if (i0 >= n) return;
    #pragma unroll
    for (int j = 0; j < 4; ++j) {
        int idx = min(i0 + j, n - 1);
        float okey, oval;
        hd_fallback(keys[idx], vals[idx], fids, bins, F, fsteps, okey, oval);
        if (i0 + j < n) { out_keys[i0 + j] = okey; out_vals[i0 + j] = oval; }
    }
}

extern "C" void kernel_launch(void* const* d_in, const int* in_sizes, int n_in,
                              void* d_out, int out_size, void* d_ws, size_t ws_size,
                              hipStream_t stream) {
    const int*   keys = (const int*)d_in[0];
    const float* vals = (const float*)d_in[1];
    const int*   fids = (const int*)d_in[2];
    const float* bins = (const float*)d_in[3];

    const int n = in_sizes[0];
    const int F = in_sizes[2];

    int fsteps = 0;
    while ((1 << fsteps) < F + 1) ++fsteps;

    float* out_keys = (float*)d_out;
    float* out_vals = (float*)d_out + n;

    // ws: qtab (2 MB) | spiv (128 KB) | scal (8 KB)
    const size_t qtab_bytes = (size_t)NPIV * 64 * sizeof(float);
    const size_t spiv_bytes = (size_t)NPIV * 16;
    const size_t scal_bytes = (size_t)NPIV;
    const size_t ws_need    = qtab_bytes + spiv_bytes + scal_bytes;
    const size_t lds_bytes  = spiv_bytes + scal_bytes;   // 139264 B

    int max_lds = 0;
    hipDeviceGetAttribute(&max_lds, hipDeviceAttributeMaxSharedMemoryPerBlock, 0);

    const bool fast = (ws_size >= ws_need) && ((size_t)max_lds >= lds_bytes) &&
                      (in_sizes[3] == F * NBIN);

    if (fast) {
        float*         qtab   = (float*)d_ws;
        ux4*           spiv_g = (ux4*)((char*)d_ws + qtab_bytes);
        unsigned char* scal_g = (unsigned char*)d_ws + qtab_bytes + spiv_bytes;

        build_tables_kernel<<<(F * 64 + 255) / 256, 256, 0, stream>>>(
            fids, bins, qtab, spiv_g, scal_g, F);

        (void)hipFuncSetAttribute(
            reinterpret_cast<const void*>(hd_main_kernel),
            hipFuncAttributeMaxDynamicSharedMemorySize, (int)lds_bytes);

        const int threads = 1024;
        const int nblocks = 256;           // 1 block/CU; LDS fill once per CU
        const int nchunks = (n + 7) / 8;
        hd_main_kernel<<<nblocks, threads, lds_bytes, stream>>>(
            keys, vals, fids, bins, qtab, spiv_g, scal_g,
            out_keys, out_vals, n, F, fsteps, nchunks);
    } else {
        const int threads = 256;
        const int grid = (n + threads * 4 - 1) / (threads * 4);
        hd_simple_kernel<<<grid, threads, 0, stream>>>(
            keys, vals, fids, bins, out_keys, out_vals, n, F, fsteps);
    }
}

// Round 3
// 218.484 us; speedup vs baseline: 1.0486x; 1.0486x over previous
//
#include <hip/hip_runtime.h>
#include <stdint.h>
#include <math.h>

// HashingDiscretizer — R8: R6 phase-separated structure, scratch bug fixed.
//
// R6/R7 post-mortem: the rare-path loop was `#pragma unroll 1` with a
// RUNTIME index j into ks/vs/ok/ov. Runtime-indexed per-thread arrays are
// demoted to scratch (local memory) for the WHOLE kernel -> every chunk
// round-tripped its working set through HBM-backed scratch (WRITE +171MB,
// FETCH +84MB, VGPR stuck at 64, launch_bounds irrelevant, 129us).
// Fix: every loop touching the per-chunk arrays is fully unrolled so all
// indices are compile-time constants; the rare path predicates each
// unrolled iteration on one bitmask bit (cold, never taken in bench data).
//
// Structure:
//   P1: 8x ds_read_b128 spiv headers (all issued back-to-back)
//   P2: classify + quadrant + gather byte-offset (dummy offset 0 for
//       uncalibrated lanes -> wave-uniform line, coalesces in TA)
//   P3: 16x global_load_dwordx4 (stage 1: first 32B of quadrant line)
//   P4: partial strict-less counts (8 of 16 bins)
//   P5: 16x global_load_dwordx4 (stage 2: last 32B, reusing registers)
//   P6: finish counts + hash + branchless select
//   cold: rare mask (key>=16384 or calibrated high key; absent in bench
//         data) -> fully-unrolled predicated fallbacks.
//
// ws layout:
//   qtab  [8192][64] f32 (2 MB): row k = 63 boundaries + inf pad; the
//          quadrant q (16 floats at +16q) is ONE 64B line.
//   spiv  [8192] uint4 (128 KB): {f32 b15, f32 b31, f32 b47, u32 k^MAGIC}
//   scal  [8192] bytes  (8 KB): for keys 8192..16383: 0x40|(k&63)
// Poison 0xAA can match neither sentinel, so unwritten rows read as
// uncalibrated — no clear pass needed.

#define GOLDEN   0x9E3779B9u
#define OUT_MASK ((1u << 22) - 1u)
#define NBIN  63
#define NPIV  8192
#define NKEY  16384
#define MAGIC 0xC0FFEE42u

typedef float fx4 __attribute__((ext_vector_type(4)));
typedef int   ix4 __attribute__((ext_vector_type(4)));
typedef unsigned ux4 __attribute__((ext_vector_type(4)));

// ---------------- build (no atomics, no clear) ----------------
__global__ __launch_bounds__(256) void build_tables_kernel(
    const int* __restrict__ fids, const float* __restrict__ bins,
    float* __restrict__ qtab, ux4* __restrict__ spiv_g,
    unsigned char* __restrict__ scal_g, int F)
{
    const int t = blockIdx.x * blockDim.x + threadIdx.x;
    if (t >= F * 64) return;
    const int r = t >> 6;
    const int j = t & 63;
    const int k = fids[r];
    const unsigned uk = (unsigned)k;
    const float* src = bins + (size_t)r * NBIN;

    if (uk < (unsigned)NPIV) {
        qtab[((size_t)uk << 6) + j] = (j < NBIN) ? src[j] : INFINITY;
        if (j == 0) {
            ux4 p;
            p.x = __float_as_uint(src[15]);
            p.y = __float_as_uint(src[31]);
            p.z = __float_as_uint(src[47]);
            p.w = uk ^ MAGIC;
            spiv_g[uk] = p;
        }
    } else if (uk < (unsigned)NKEY && j == 0) {
        scal_g[uk - NPIV] = (unsigned char)(0x40u | (uk & 63u));
    }
}

// ---------------- generic fallback ----------------
__device__ __forceinline__ void hd_fallback(
    int k, float v, const int* __restrict__ fids, const float* __restrict__ bins,
    int F, int fsteps, float& okey, float& oval)
{
    int lo = 0, hi = F;
    for (int s = 0; s < fsteps; ++s) {
        int  mid  = (lo + hi) >> 1;
        int  mids = min(mid, F - 1);
        int  fv   = fids[mids];
        bool valid = lo < hi;
        bool right = valid && (fv < k);
        lo = right ? mid + 1 : lo;
        hi = (valid && !right) ? mid : hi;
    }
    const int  idx_safe   = min(lo, F - 1);
    const bool calibrated = (fids[idx_safe] == k);
    const float* brow = bins + (size_t)idx_safe * NBIN;
    int blo = 0, bhi = NBIN;
    #pragma unroll
    for (int s = 0; s < 6; ++s) {
        int   mid  = (blo + bhi) >> 1;
        int   mids = min(mid, NBIN - 1);
        float bv   = brow[mids];
        bool  valid = blo < bhi;
        bool  right = valid && (bv < v);
        blo = right ? mid + 1 : blo;
        bhi = (valid && !right) ? mid : bhi;
    }
    const uint32_t h = ((uint32_t)k * GOLDEN + (uint32_t)blo) * GOLDEN;
    okey = calibrated ? (float)(h & OUT_MASK) : (float)((uint32_t)k & OUT_MASK);
    oval = calibrated ? 1.0f : v;
}

// ---------------- main ----------------
// LDS (139KB) forces 1 block/CU = 4 waves/SIMD; declare it so the register
// allocator uses the full 512/4 = 128 VGPR budget.
__global__ __launch_bounds__(1024, 4) void hd_main_kernel(
    const int* __restrict__ keys, const float* __restrict__ vals,
    const int* __restrict__ fids, const float* __restrict__ bins,
    const float* __restrict__ qtab, const ux4* __restrict__ spiv_g,
    const unsigned char* __restrict__ scal_g,
    float* __restrict__ out_keys, float* __restrict__ out_vals,
    int n, int F, int fsteps, int nchunks)
{
    extern __shared__ char smem[];
    ux4*      spiv = reinterpret_cast<ux4*>(smem);               // NPIV x 16B
    unsigned* scal = reinterpret_cast<unsigned*>(smem + (size_t)NPIV * 16);

    const int tid = threadIdx.x;
    for (int i = tid; i < NPIV; i += (int)blockDim.x) spiv[i] = spiv_g[i];
    const unsigned* scal_g32 = reinterpret_cast<const unsigned*>(scal_g);
    for (int i = tid; i < NPIV / 4; i += (int)blockDim.x) scal[i] = scal_g32[i];
    __syncthreads();

    const unsigned char* scal_b = reinterpret_cast<const unsigned char*>(scal);
    const char* qb = reinterpret_cast<const char*>(qtab);
    const int nthreads = (int)(gridDim.x * blockDim.x);

    for (int c = blockIdx.x * blockDim.x + tid; c < nchunks; c += nthreads) {
        const int i0 = c * 8;
        int   ks[8];
        float vs[8];
        const bool full = (i0 + 7 < n);
        if (full) {
            const ix4 ka = __builtin_nontemporal_load(reinterpret_cast<const ix4*>(keys + i0));
            const ix4 kb = __builtin_nontemporal_load(reinterpret_cast<const ix4*>(keys + i0 + 4));
            const fx4 va = __builtin_nontemporal_load(reinterpret_cast<const fx4*>(vals + i0));
            const fx4 vb = __builtin_nontemporal_load(reinterpret_cast<const fx4*>(vals + i0 + 4));
            ks[0]=ka.x; ks[1]=ka.y; ks[2]=ka.z; ks[3]=ka.w;
            ks[4]=kb.x; ks[5]=kb.y; ks[6]=kb.z; ks[7]=kb.w;
            vs[0]=va.x; vs[1]=va.y; vs[2]=va.z; vs[3]=va.w;
            vs[4]=vb.x; vs[5]=vb.y; vs[6]=vb.z; vs[7]=vb.w;
        } else {
            #pragma unroll
            for (int j = 0; j < 8; ++j) {
                int idx = min(i0 + j, n - 1);
                ks[j] = keys[idx];
                vs[j] = vals[idx];
            }
        }

        // ---- P1: all 8 spiv headers (independent ds_read_b128) ----
        ux4 hdr[8];
        #pragma unroll
        for (int j = 0; j < 8; ++j) {
            const unsigned uk = (unsigned)ks[j];
            hdr[j] = spiv[uk < (unsigned)NPIV ? uk : 0u];
        }

        // ---- P2: classify, quadrant, byte offsets, rare mask ----
        unsigned off[8];
        int      qcnt[8];
        unsigned calm = 0u, rare = 0u;
        #pragma unroll
        for (int j = 0; j < 8; ++j) {
            const unsigned uk = (unsigned)ks[j];
            const float v = vs[j];
            const bool low = uk < (unsigned)NPIV;
            const bool cal = low && (hdr[j].w == (uk ^ MAGIC));
            const int q = (__uint_as_float(hdr[j].x) < v)
                        + (__uint_as_float(hdr[j].y) < v)
                        + (__uint_as_float(hdr[j].z) < v);
            off[j]  = cal ? ((uk << 8) + (unsigned)(q << 6)) : 0u;
            qcnt[j] = q << 4;
            calm   |= cal ? (1u << j) : 0u;
            // high-key calibrated check (LDS byte, branchless)
            const unsigned hs = uk - (unsigned)NPIV;
            const bool hi = hs < (unsigned)NPIV;            // NPIV<=uk<NKEY
            const bool calhi = hi && (scal_b[hi ? hs : 0u]
                              == (unsigned char)(0x40u | (uk & 63u)));
            rare |= (calhi || (uk >= (unsigned)NKEY)) ? (1u << j) : 0u;
        }

        // ---- P3: stage-1 gathers (first 32B of quadrant line) ----
        fx4 gA[8], gB[8];
        #pragma unroll
        for (int j = 0; j < 8; ++j) {
            const char* p = qb + off[j];
            gA[j] = *reinterpret_cast<const fx4*>(p);
            gB[j] = *reinterpret_cast<const fx4*>(p + 16);
        }
        // ---- P4: partial counts ----
        #pragma unroll
        for (int j = 0; j < 8; ++j) {
            const float v = vs[j];
            qcnt[j] += (gA[j].x<v)+(gA[j].y<v)+(gA[j].z<v)+(gA[j].w<v)
                     + (gB[j].x<v)+(gB[j].y<v)+(gB[j].z<v)+(gB[j].w<v);
        }
        // ---- P5: stage-2 gathers (last 32B, registers reused) ----
        #pragma unroll
        for (int j = 0; j < 8; ++j) {
            const char* p = qb + off[j];
            gA[j] = *reinterpret_cast<const fx4*>(p + 32);
            gB[j] = *reinterpret_cast<const fx4*>(p + 48);
        }
        // ---- P6: finish counts + hash + branchless select ----
        float ok[8], ov[8];
        #pragma unroll
        for (int j = 0; j < 8; ++j) {
            const unsigned uk = (unsigned)ks[j];
            const float v = vs[j];
            const int cnt = qcnt[j]
                + (gA[j].x<v)+(gA[j].y<v)+(gA[j].z<v)+(gA[j].w<v)
                + (gB[j].x<v)+(gB[j].y<v)+(gB[j].z<v)+(gB[j].w<v);
            const uint32_t h = (uk * GOLDEN + (uint32_t)cnt) * GOLDEN;
            const bool cal = (calm >> j) & 1u;
            ok[j] = cal ? (float)(h & OUT_MASK) : (float)(uk & OUT_MASK);
            ov[j] = cal ? 1.0f : v;
        }

        // ---- cold path: key>=NKEY or calibrated high key (never in bench)
        // FULLY UNROLLED: j is compile-time, so ks/vs/ok/ov stay in
        // registers (runtime-indexed arrays are demoted to scratch).
        if (__builtin_expect(rare != 0u, 0)) {
            #pragma unroll
            for (int j = 0; j < 8; ++j)
                if ((rare >> j) & 1u)
                    hd_fallback(ks[j], vs[j], fids, bins, F, fsteps, ok[j], ov[j]);
        }

        if (full) {
            fx4 a, b;
            a.x=ok[0]; a.y=ok[1]; a.z=ok[2]; a.w=ok[3];
            b.x=ok[4]; b.y=ok[5]; b.z=ok[6]; b.w=ok[7];
            __builtin_nontemporal_store(a, reinterpret_cast<fx4*>(out_keys + i0));
            __builtin_nontemporal_store(b, reinterpret_cast<fx4*>(out_keys + i0 + 4));
            a.x=ov[0]; a.y=ov[1]; a.z=ov[2]; a.w=ov[3];
            b.x=ov[4]; b.y=ov[5]; b.z=ov[6]; b.w=ov[7];
            __builtin_nontemporal_store(a, reinterpret_cast<fx4*>(out_vals + i0));
            __builtin_nontemporal_store(b, reinterpret_cast<fx4*>(out_vals + i0 + 4));
        } else {
            #pragma unroll
            for (int j = 0; j < 8; ++j) {
                if (i0 + j < n) {
                    out_keys[i0 + j] = ok[j];
                    out_vals[i0 + j] = ov[j];
                }
            }
        }
    }
}

// Pure binary-search kernel: used only if LDS or workspace is insufficient.
__global__ __launch_bounds__(256) void hd_simple_kernel(
    const int* __restrict__ keys, const float* __restrict__ vals,
    const int* __restrict__ fids, const float* __restrict__ bins,
    float* __restrict__ out_keys, float* __restrict__ out_vals,
    int n, int F, int fsteps)
{
    const int gid = blockIdx.x * blockDim.x + threadIdx.x;
    const int i0 = gid * 4;
    if (i0 >= n) return;
    #pragma unroll
    for (int j = 0; j < 4; ++j) {
        int idx = min(i0 + j, n - 1);
        float okey, oval;
        hd_fallback(keys[idx], vals[idx], fids, bins, F, fsteps, okey, oval);
        if (i0 + j < n) { out_keys[i0 + j] = okey; out_vals[i0 + j] = oval; }
    }
}

extern "C" void kernel_launch(void* const* d_in, const int* in_sizes, int n_in,
                              void* d_out, int out_size, void* d_ws, size_t ws_size,
                              hipStream_t stream) {
    const int*   keys = (const int*)d_in[0];
    const float* vals = (const float*)d_in[1];
    const int*   fids = (const int*)d_in[2];
    const float* bins = (const float*)d_in[3];

    const int n = in_sizes[0];
    const int F = in_sizes[2];

    int fsteps = 0;
    while ((1 << fsteps) < F + 1) ++fsteps;

    float* out_keys = (float*)d_out;
    float* out_vals = (float*)d_out + n;

    // ws: qtab (2 MB) | spiv (128 KB) | scal (8 KB)
    const size_t qtab_bytes = (size_t)NPIV * 64 * sizeof(float);
    const size_t spiv_bytes = (size_t)NPIV * 16;
    const size_t scal_bytes = (size_t)NPIV;
    const size_t ws_need    = qtab_bytes + spiv_bytes + scal_bytes;
    const size_t lds_bytes  = spiv_bytes + scal_bytes;   // 139264 B

    int max_lds = 0;
    hipDeviceGetAttribute(&max_lds, hipDeviceAttributeMaxSharedMemoryPerBlock, 0);

    const bool fast = (ws_size >= ws_need) && ((size_t)max_lds >= lds_bytes) &&
                      (in_sizes[3] == F * NBIN);

    if (fast) {
        float*         qtab   = (float*)d_ws;
        ux4*           spiv_g = (ux4*)((char*)d_ws + qtab_bytes);
        unsigned char* scal_g = (unsigned char*)d_ws + qtab_bytes + spiv_bytes;

        build_tables_kernel<<<(F * 64 + 255) / 256, 256, 0, stream>>>(
            fids, bins, qtab, spiv_g, scal_g, F);

        (void)hipFuncSetAttribute(
            reinterpret_cast<const void*>(hd_main_kernel),
            hipFuncAttributeMaxDynamicSharedMemorySize, (int)lds_bytes);

        const int threads = 1024;
        const int nblocks = 256;           // 1 block/CU; LDS fill once per CU
        const int nchunks = (n + 7) / 8;
        hd_main_kernel<<<nblocks, threads, lds_bytes, stream>>>(
            keys, vals, fids, bins, qtab, spiv_g, scal_g,
            out_keys, out_vals, n, F, fsteps, nchunks);
    } else {
        const int threads = 256;
        const int grid = (n + threads * 4 - 1) / (threads * 4);
        hd_simple_kernel<<<grid, threads, 0, stream>>>(
            keys, vals, fids, bins, out_keys, out_vals, n, F, fsteps);
    }
}

// Round 4
// 164.871 us; speedup vs baseline: 1.3896x; 1.3252x over previous
//
#include <hip/hip_runtime.h>
#include <stdint.h>
#include <math.h>

// HashingDiscretizer — R9: phase-separated MLP, live set sized to the
// compiler's actual 64-VGPR cap; NO per-thread arrays (named scalars only).
//
// R6-R8 post-mortem: VGPR_Count pinned at 64 across three rounds; the
// 8-elem phase-separated chunk needs ~110 live regs -> ~40 regs spilled
// to scratch per chunk = the observed +150MB WRITE / +85MB FETCH and 2x
// slowdown. __launch_bounds__(1024,4) did NOT lift the cap (dynamic LDS
// is invisible at compile time; backend occupancy heuristic wins).
// Fix: 4-element chunks with named scalars -> peak live set ~58 VGPRs,
// fits the cap; 8 gathers in flight per wave x 4 waves/SIMD = 32
// outstanding per SIMD, still enough MLP to cover L2 latency.
//
// Per chunk (4 elems):
//   P1: 4x ds_read_b128 spiv headers
//   P2: classify + quadrant + byte offset (dummy 0 if uncalibrated ->
//       wave-uniform broadcast line, ~free in TA)
//   P3: 8x global_load_dwordx4 (first 32B of each quadrant line)
//   P4: partial counts (8 of 16 bins)
//   P5: 8x global_load_dwordx4 (last 32B, same registers)
//   P6: finish counts + hash + branchless select
//   cold: named-scalar fallbacks (never taken in bench data)
//
// ws layout:
//   qtab  [8192][64] f32 (2 MB): row k = 63 boundaries + inf pad; the
//          quadrant q (16 floats at +16q) is ONE 64B line.
//   spiv  [8192] uint4 (128 KB): {f32 b15, f32 b31, f32 b47, u32 k^MAGIC}
//   scal  [8192] bytes  (8 KB): for keys 8192..16383: 0x40|(k&63)
// Poison 0xAA matches neither sentinel -> unwritten rows read as
// uncalibrated; no clear pass needed.

#define GOLDEN   0x9E3779B9u
#define OUT_MASK ((1u << 22) - 1u)
#define NBIN  63
#define NPIV  8192
#define NKEY  16384
#define MAGIC 0xC0FFEE42u

typedef float fx4 __attribute__((ext_vector_type(4)));
typedef int   ix4 __attribute__((ext_vector_type(4)));
typedef unsigned ux4 __attribute__((ext_vector_type(4)));

// ---------------- build (no atomics, no clear) ----------------
__global__ __launch_bounds__(256) void build_tables_kernel(
    const int* __restrict__ fids, const float* __restrict__ bins,
    float* __restrict__ qtab, ux4* __restrict__ spiv_g,
    unsigned char* __restrict__ scal_g, int F)
{
    const int t = blockIdx.x * blockDim.x + threadIdx.x;
    if (t >= F * 64) return;
    const int r = t >> 6;
    const int j = t & 63;
    const int k = fids[r];
    const unsigned uk = (unsigned)k;
    const float* src = bins + (size_t)r * NBIN;

    if (uk < (unsigned)NPIV) {
        qtab[((size_t)uk << 6) + j] = (j < NBIN) ? src[j] : INFINITY;
        if (j == 0) {
            ux4 p;
            p.x = __float_as_uint(src[15]);
            p.y = __float_as_uint(src[31]);
            p.z = __float_as_uint(src[47]);
            p.w = uk ^ MAGIC;
            spiv_g[uk] = p;
        }
    } else if (uk < (unsigned)NKEY && j == 0) {
        scal_g[uk - NPIV] = (unsigned char)(0x40u | (uk & 63u));
    }
}

// ---------------- generic fallback ----------------
__device__ __forceinline__ void hd_fallback(
    int k, float v, const int* __restrict__ fids, const float* __restrict__ bins,
    int F, int fsteps, float& okey, float& oval)
{
    int lo = 0, hi = F;
    for (int s = 0; s < fsteps; ++s) {
        int  mid  = (lo + hi) >> 1;
        int  mids = min(mid, F - 1);
        int  fv   = fids[mids];
        bool valid = lo < hi;
        bool right = valid && (fv < k);
        lo = right ? mid + 1 : lo;
        hi = (valid && !right) ? mid : hi;
    }
    const int  idx_safe   = min(lo, F - 1);
    const bool calibrated = (fids[idx_safe] == k);
    const float* brow = bins + (size_t)idx_safe * NBIN;
    int blo = 0, bhi = NBIN;
    #pragma unroll
    for (int s = 0; s < 6; ++s) {
        int   mid  = (blo + bhi) >> 1;
        int   mids = min(mid, NBIN - 1);
        float bv   = brow[mids];
        bool  valid = blo < bhi;
        bool  right = valid && (bv < v);
        blo = right ? mid + 1 : blo;
        bhi = (valid && !right) ? mid : bhi;
    }
    const uint32_t h = ((uint32_t)k * GOLDEN + (uint32_t)blo) * GOLDEN;
    okey = calibrated ? (float)(h & OUT_MASK) : (float)((uint32_t)k & OUT_MASK);
    oval = calibrated ? 1.0f : v;
}

__device__ __forceinline__ int hd_cmp8(fx4 a, fx4 b, float v) {
    return (a.x < v) + (a.y < v) + (a.z < v) + (a.w < v)
         + (b.x < v) + (b.y < v) + (b.z < v) + (b.w < v);
}

// ---------------- main ----------------
__global__ __launch_bounds__(1024, 4) void hd_main_kernel(
    const int* __restrict__ keys, const float* __restrict__ vals,
    const int* __restrict__ fids, const float* __restrict__ bins,
    const float* __restrict__ qtab, const ux4* __restrict__ spiv_g,
    const unsigned char* __restrict__ scal_g,
    float* __restrict__ out_keys, float* __restrict__ out_vals,
    int n, int F, int fsteps, int nchunks)
{
    extern __shared__ char smem[];
    ux4*      spiv = reinterpret_cast<ux4*>(smem);               // NPIV x 16B
    unsigned* scal = reinterpret_cast<unsigned*>(smem + (size_t)NPIV * 16);

    const int tid = threadIdx.x;
    for (int i = tid; i < NPIV; i += (int)blockDim.x) spiv[i] = spiv_g[i];
    const unsigned* scal_g32 = reinterpret_cast<const unsigned*>(scal_g);
    for (int i = tid; i < NPIV / 4; i += (int)blockDim.x) scal[i] = scal_g32[i];
    __syncthreads();

    const unsigned char* scal_b = reinterpret_cast<const unsigned char*>(scal);
    const char* qb = reinterpret_cast<const char*>(qtab);
    const int nthreads = (int)(gridDim.x * blockDim.x);

    for (int c = blockIdx.x * blockDim.x + tid; c < nchunks; c += nthreads) {
        const int i0 = c * 4;
        int   k0, k1, k2, k3;
        float v0, v1, v2, v3;
        const bool full = (i0 + 3 < n);
        if (full) {
            const ix4 ka = __builtin_nontemporal_load(reinterpret_cast<const ix4*>(keys + i0));
            const fx4 va = __builtin_nontemporal_load(reinterpret_cast<const fx4*>(vals + i0));
            k0 = ka.x; k1 = ka.y; k2 = ka.z; k3 = ka.w;
            v0 = va.x; v1 = va.y; v2 = va.z; v3 = va.w;
        } else {
            k0 = keys[min(i0 + 0, n - 1)]; v0 = vals[min(i0 + 0, n - 1)];
            k1 = keys[min(i0 + 1, n - 1)]; v1 = vals[min(i0 + 1, n - 1)];
            k2 = keys[min(i0 + 2, n - 1)]; v2 = vals[min(i0 + 2, n - 1)];
            k3 = keys[min(i0 + 3, n - 1)]; v3 = vals[min(i0 + 3, n - 1)];
        }

        // ---- P1: 4 spiv headers, issued back-to-back ----
        const unsigned u0 = (unsigned)k0, u1 = (unsigned)k1,
                       u2 = (unsigned)k2, u3 = (unsigned)k3;
        const ux4 h0 = spiv[u0 < (unsigned)NPIV ? u0 : 0u];
        const ux4 h1 = spiv[u1 < (unsigned)NPIV ? u1 : 0u];
        const ux4 h2 = spiv[u2 < (unsigned)NPIV ? u2 : 0u];
        const ux4 h3 = spiv[u3 < (unsigned)NPIV ? u3 : 0u];

        // ---- P2: classify, quadrant, byte offset, rare flags ----
#define HD_P2(J)                                                              \
        const bool cal##J = (u##J < (unsigned)NPIV) &&                        \
                            (h##J.w == (u##J ^ MAGIC));                       \
        const int  q##J = (__uint_as_float(h##J.x) < v##J)                    \
                        + (__uint_as_float(h##J.y) < v##J)                    \
                        + (__uint_as_float(h##J.z) < v##J);                   \
        const unsigned off##J = cal##J ? ((u##J << 8) + (unsigned)(q##J << 6))\
                                       : 0u;                                  \
        int qc##J = q##J << 4;                                                \
        const unsigned hs##J = u##J - (unsigned)NPIV;                         \
        const bool rare##J =                                                  \
            (u##J >= (unsigned)NKEY) ||                                       \
            ((hs##J < (unsigned)NPIV) &&                                      \
             (scal_b[hs##J < (unsigned)NPIV ? hs##J : 0u] ==                  \
              (unsigned char)(0x40u | (u##J & 63u))));
        HD_P2(0) HD_P2(1) HD_P2(2) HD_P2(3)
#undef HD_P2

        // ---- P3: stage-1 gathers (first 32B of quadrant line) ----
        fx4 a0 = *reinterpret_cast<const fx4*>(qb + off0);
        fx4 b0 = *reinterpret_cast<const fx4*>(qb + off0 + 16);
        fx4 a1 = *reinterpret_cast<const fx4*>(qb + off1);
        fx4 b1 = *reinterpret_cast<const fx4*>(qb + off1 + 16);
        fx4 a2 = *reinterpret_cast<const fx4*>(qb + off2);
        fx4 b2 = *reinterpret_cast<const fx4*>(qb + off2 + 16);
        fx4 a3 = *reinterpret_cast<const fx4*>(qb + off3);
        fx4 b3 = *reinterpret_cast<const fx4*>(qb + off3 + 16);

        // ---- P4: partial counts ----
        qc0 += hd_cmp8(a0, b0, v0);
        qc1 += hd_cmp8(a1, b1, v1);
        qc2 += hd_cmp8(a2, b2, v2);
        qc3 += hd_cmp8(a3, b3, v3);

        // ---- P5: stage-2 gathers (last 32B, same registers) ----
        a0 = *reinterpret_cast<const fx4*>(qb + off0 + 32);
        b0 = *reinterpret_cast<const fx4*>(qb + off0 + 48);
        a1 = *reinterpret_cast<const fx4*>(qb + off1 + 32);
        b1 = *reinterpret_cast<const fx4*>(qb + off1 + 48);
        a2 = *reinterpret_cast<const fx4*>(qb + off2 + 32);
        b2 = *reinterpret_cast<const fx4*>(qb + off2 + 48);
        a3 = *reinterpret_cast<const fx4*>(qb + off3 + 32);
        b3 = *reinterpret_cast<const fx4*>(qb + off3 + 48);

        // ---- P6: finish counts + hash + branchless select ----
        float ok0, ok1, ok2, ok3, ov0, ov1, ov2, ov3;
#define HD_P6(J)                                                              \
        {                                                                     \
            const int cnt = qc##J + hd_cmp8(a##J, b##J, v##J);                \
            const uint32_t h = (u##J * GOLDEN + (uint32_t)cnt) * GOLDEN;      \
            ok##J = cal##J ? (float)(h & OUT_MASK) : (float)(u##J & OUT_MASK);\
            ov##J = cal##J ? 1.0f : v##J;                                     \
        }
        HD_P6(0) HD_P6(1) HD_P6(2) HD_P6(3)
#undef HD_P6

        // ---- cold path (absent in bench data) ----
        if (__builtin_expect(rare0 | rare1 | rare2 | rare3, 0)) {
            if (rare0) hd_fallback(k0, v0, fids, bins, F, fsteps, ok0, ov0);
            if (rare1) hd_fallback(k1, v1, fids, bins, F, fsteps, ok1, ov1);
            if (rare2) hd_fallback(k2, v2, fids, bins, F, fsteps, ok2, ov2);
            if (rare3) hd_fallback(k3, v3, fids, bins, F, fsteps, ok3, ov3);
        }

        if (full) {
            fx4 s;
            s.x = ok0; s.y = ok1; s.z = ok2; s.w = ok3;
            __builtin_nontemporal_store(s, reinterpret_cast<fx4*>(out_keys + i0));
            s.x = ov0; s.y = ov1; s.z = ov2; s.w = ov3;
            __builtin_nontemporal_store(s, reinterpret_cast<fx4*>(out_vals + i0));
        } else {
            if (i0 + 0 < n) { out_keys[i0 + 0] = ok0; out_vals[i0 + 0] = ov0; }
            if (i0 + 1 < n) { out_keys[i0 + 1] = ok1; out_vals[i0 + 1] = ov1; }
            if (i0 + 2 < n) { out_keys[i0 + 2] = ok2; out_vals[i0 + 2] = ov2; }
            if (i0 + 3 < n) { out_keys[i0 + 3] = ok3; out_vals[i0 + 3] = ov3; }
        }
    }
}

// Pure binary-search kernel: used only if LDS or workspace is insufficient.
__global__ __launch_bounds__(256) void hd_simple_kernel(
    const int* __restrict__ keys, const float* __restrict__ vals,
    const int* __restrict__ fids, const float* __restrict__ bins,
    float* __restrict__ out_keys, float* __restrict__ out_vals,
    int n, int F, int fsteps)
{
    const int gid = blockIdx.x * blockDim.x + threadIdx.x;
    const int i0 = gid * 4;
    if (i0 >= n) return;
    #pragma unroll
    for (int j = 0; j < 4; ++j) {
        int idx = min(i0 + j, n - 1);
        float okey, oval;
        hd_fallback(keys[idx], vals[idx], fids, bins, F, fsteps, okey, oval);
        if (i0 + j < n) { out_keys[i0 + j] = okey; out_vals[i0 + j] = oval; }
    }
}

extern "C" void kernel_launch(void* const* d_in, const int* in_sizes, int n_in,
                              void* d_out, int out_size, void* d_ws, size_t ws_size,
                              hipStream_t stream) {
    const int*   keys = (const int*)d_in[0];
    const float* vals = (const float*)d_in[1];
    const int*   fids = (const int*)d_in[2];
    const float* bins = (const float*)d_in[3];

    const int n = in_sizes[0];
    const int F = in_sizes[2];

    int fsteps = 0;
    while ((1 << fsteps) < F + 1) ++fsteps;

    float* out_keys = (float*)d_out;
    float* out_vals = (float*)d_out + n;

    // ws: qtab (2 MB) | spiv (128 KB) | scal (8 KB)
    const size_t qtab_bytes = (size_t)NPIV * 64 * sizeof(float);
    const size_t spiv_bytes = (size_t)NPIV * 16;
    const size_t scal_bytes = (size_t)NPIV;
    const size_t ws_need    = qtab_bytes + spiv_bytes + scal_bytes;
    const size_t lds_bytes  = spiv_bytes + scal_bytes;   // 139264 B

    int max_lds = 0;
    hipDeviceGetAttribute(&max_lds, hipDeviceAttributeMaxSharedMemoryPerBlock, 0);

    const bool fast = (ws_size >= ws_need) && ((size_t)max_lds >= lds_bytes) &&
                      (in_sizes[3] == F * NBIN);

    if (fast) {
        float*         qtab   = (float*)d_ws;
        ux4*           spiv_g = (ux4*)((char*)d_ws + qtab_bytes);
        unsigned char* scal_g = (unsigned char*)d_ws + qtab_bytes + spiv_bytes;

        build_tables_kernel<<<(F * 64 + 255) / 256, 256, 0, stream>>>(
            fids, bins, qtab, spiv_g, scal_g, F);

        (void)hipFuncSetAttribute(
            reinterpret_cast<const void*>(hd_main_kernel),
            hipFuncAttributeMaxDynamicSharedMemorySize, (int)lds_bytes);

        const int threads = 1024;
        const int nblocks = 256;           // 1 block/CU; LDS fill once per CU
        const int nchunks = (n + 3) / 4;
        hd_main_kernel<<<nblocks, threads, lds_bytes, stream>>>(
            keys, vals, fids, bins, qtab, spiv_g, scal_g,
            out_keys, out_vals, n, F, fsteps, nchunks);
    } else {
        const int threads = 256;
        const int grid = (n + threads * 4 - 1) / (threads * 4);
        hd_simple_kernel<<<grid, threads, 0, stream>>>(
            keys, vals, fids, bins, out_keys, out_vals, n, F, fsteps);
    }
}